// Round 2
// baseline (265.641 us; speedup 1.0000x reference)
//
#include <hip/hip_runtime.h>

// QuantizedConv1d on MI355X (gfx950)
// B=32, CIN=128, L=4096, COUT=256, K=5, replication pad 2.
// Pipeline:
//   prep_kernel: x f32 -> XqT bf16 [B][4100][128] (quantized, transposed,
//                edge-pad rows materialized); W int32 -> Wt bf16 [5][256][128]
//   conv_kernel: bf16 MFMA 16x16x32 GEMM (exact integer arithmetic in bf16/f32),
//                per-channel requant epilogue, int32 output (int8 values).
// Workspace use: 33,914,880 bytes.

#define B_    32
#define CIN   128
#define LEN   4096
#define COUT  256
#define KW    5
#define LROWS 4100  // LEN + 4 pad rows

#define XQT_USHORTS ((size_t)B_ * LROWS * CIN)  // 16,793,600
#define WT_USHORTS  ((size_t)KW * COUT * CIN)   // 163,840

typedef float          f32x4 __attribute__((ext_vector_type(4)));
typedef short          s16x8 __attribute__((ext_vector_type(8)));
typedef unsigned short u16;
typedef u16            u16x4 __attribute__((ext_vector_type(4)));

// Quantize one float to int8 domain, return bf16 bit pattern of the integer.
// Matches reference exactly: round-half-even(x / 0.05) - 3, clip [-128,127].
// IEEE division (NOT mul by reciprocal) to match jnp bit-for-bit at .5 edges.
// Integers |v| <= 128 are exact in bf16 (8-bit significand), low 16 bits zero.
__device__ __forceinline__ u16 quant_bf16(float xv) {
    float q = rintf(__fdiv_rn(xv, 0.05f)) - 3.0f;
    q = fminf(fmaxf(q, -128.0f), 127.0f);
    return (u16)(__float_as_uint(q) >> 16);
}

__global__ __launch_bounds__(256) void prep_kernel(
        const float* __restrict__ x, const int* __restrict__ w,
        u16* __restrict__ xqt, u16* __restrict__ wt)
{
    int bid = blockIdx.x;
    int t   = threadIdx.x;
    if (bid < 512) {
        // ---- X: quantize + transpose one [128 ci][256 l] slab ----
        int b = bid >> 4, slab = bid & 15;
        int l0 = slab << 8;
        const float* xb = x + (size_t)b * CIN * LEN;
        u16* ob = xqt + (size_t)b * LROWS * CIN;
        #pragma unroll
        for (int i = 0; i < 8; ++i) {
            int st = t + (i << 8);            // 0..2047 subtiles (4ci x 4l)
            int l4 = st & 63, c4 = st >> 6;   // lanes consecutive in l -> coalesced reads
            int ci = c4 << 2, ll = (l4 << 2) + l0;
            u16 q[4][4];
            #pragma unroll
            for (int j = 0; j < 4; ++j) {
                f32x4 f = *(const f32x4*)(xb + (size_t)(ci + j) * LEN + ll);
                #pragma unroll
                for (int m = 0; m < 4; ++m) q[j][m] = quant_bf16(f[m]);
            }
            #pragma unroll
            for (int m = 0; m < 4; ++m) {     // 4x4 register transpose, 8B stores
                u16x4 v = { q[0][m], q[1][m], q[2][m], q[3][m] };
                *(u16x4*)(ob + (size_t)(2 + ll + m) * CIN + ci) = v;
            }
        }
        // ---- replication pad rows ----
        if (slab == 0 && t < 32) {
            int ci = t << 2;
            u16 q[4];
            #pragma unroll
            for (int j = 0; j < 4; ++j) q[j] = quant_bf16(xb[(size_t)(ci + j) * LEN]);
            u16x4 v = { q[0], q[1], q[2], q[3] };
            *(u16x4*)(ob + ci) = v;
            *(u16x4*)(ob + CIN + ci) = v;
        }
        if (slab == 15 && t >= 32 && t < 64) {
            int ci = (t - 32) << 2;
            u16 q[4];
            #pragma unroll
            for (int j = 0; j < 4; ++j) q[j] = quant_bf16(xb[(size_t)(ci + j) * LEN + (LEN - 1)]);
            u16x4 v = { q[0], q[1], q[2], q[3] };
            *(u16x4*)(ob + (size_t)4098 * CIN + ci) = v;
            *(u16x4*)(ob + (size_t)4099 * CIN + ci) = v;
        }
    } else {
        // ---- W: [256 co][128 ci][5 k] int32 -> Wt bf16 [5 k][256 co][128 ci] ----
        int o  = ((bid - 512) << 8) + t;      // 0..40959, 4 ci each
        int c4 = o & 31, co = (o >> 5) & 255, k = o >> 13;
        int ci = c4 << 2;
        u16 q[4];
        #pragma unroll
        for (int j = 0; j < 4; ++j) {
            float f = (float)w[co * (CIN * KW) + (ci + j) * KW + k];  // |v|<=127 exact
            q[j] = (u16)(__float_as_uint(f) >> 16);
        }
        u16x4 v4 = { q[0], q[1], q[2], q[3] };
        *(u16x4*)(wt + ((size_t)k * COUT + co) * CIN + ci) = v4;
    }
}

// 16 waves: wave (wid&7) -> 32 output channels, (wid>>3) -> 64 l positions.
// A = Wt (M=co, K=ci), B = XqT (K=ci, N=l). K-loop: 5 taps x 4 ci-quarters.
// No LDS this round: W slices are L2-resident (320 KB), X tile is L1-resident.
__global__ __launch_bounds__(1024, 4) void conv_kernel(
        const u16* __restrict__ xqt, const u16* __restrict__ wt,
        const int* __restrict__ bias, const float* __restrict__ wscale,
        int* __restrict__ out)
{
    int bid = blockIdx.x;
    int b  = bid >> 5;
    int l0 = (bid & 31) << 7;
    int tid = threadIdx.x;
    int wid = tid >> 6, lane = tid & 63;
    int co_base = (wid & 7) << 5;
    int l_base  = l0 + ((wid >> 3) << 6);
    int lr = lane & 15, lh = lane >> 4;
    const u16* xb = xqt + (size_t)b * LROWS * CIN;

    f32x4 acc[2][4] = {};
    for (int k = 0; k < KW; ++k) {
        #pragma unroll
        for (int s = 0; s < 4; ++s) {
            int ci0 = (s << 5) + (lh << 3);
            s16x8 af[2];
            #pragma unroll
            for (int ct = 0; ct < 2; ++ct)
                af[ct] = *(const s16x8*)(wt + ((size_t)k * COUT + co_base + ct * 16 + lr) * CIN + ci0);
            s16x8 bfr[4];
            #pragma unroll
            for (int lt = 0; lt < 4; ++lt)
                bfr[lt] = *(const s16x8*)(xb + (size_t)(l_base + lt * 16 + lr + k) * CIN + ci0);
            #pragma unroll
            for (int ct = 0; ct < 2; ++ct) {
                #pragma unroll
                for (int lt = 0; lt < 4; ++lt)
                    acc[ct][lt] = __builtin_amdgcn_mfma_f32_16x16x32_bf16(
                        af[ct], bfr[lt], acc[ct][lt], 0, 0, 0);
            }
        }
    }

    // Requant epilogue. acc holds exact integer conv sums (|sum| < 2^24).
    // scale computed exactly as reference: (0.05f * ws) / 0.1f, then
    // non-contracted mul/add so rounding matches JAX bit-for-bit.
    // Output dtype is int32 (harness reads np.int32 for integer references).
    #pragma unroll
    for (int ct = 0; ct < 2; ++ct) {
        #pragma unroll
        for (int r = 0; r < 4; ++r) {
            int co = co_base + ct * 16 + (lh << 2) + r;
            float sc = __fdiv_rn(__fmul_rn(0.05f, wscale[co]), 0.1f);
            float bs = (float)bias[co];
            #pragma unroll
            for (int lt = 0; lt < 4; ++lt) {
                int l = l_base + lt * 16 + lr;
                float a = __fadd_rn(acc[ct][lt][r], bs);
                float o = __fadd_rn(__fmul_rn(a, sc), -128.0f);
                o = rintf(o);
                o = fminf(fmaxf(o, -128.0f), 127.0f);
                out[((size_t)b * COUT + co) * LEN + l] = (int)o;
            }
        }
    }
}

extern "C" void kernel_launch(void* const* d_in, const int* in_sizes, int n_in,
                              void* d_out, int out_size, void* d_ws, size_t ws_size,
                              hipStream_t stream)
{
    const float* x    = (const float*)d_in[0];
    const int*   w    = (const int*)d_in[1];
    const int*   bias = (const int*)d_in[2];
    const float* wsc  = (const float*)d_in[3];
    int* out = (int*)d_out;

    u16* xqt = (u16*)d_ws;
    u16* wt  = xqt + XQT_USHORTS;   // needs 33,914,880 bytes total

    prep_kernel<<<dim3(512 + 160), dim3(256), 0, stream>>>(x, w, xqt, wt);
    conv_kernel<<<dim3(B_ * (LEN / 128)), dim3(1024), 0, stream>>>(xqt, wt, bias, wsc, out);
}

// Round 3
// 141.673 us; speedup vs baseline: 1.8750x; 1.8750x over previous
//
#include <hip/hip_runtime.h>

// QuantizedConv1d on MI355X (gfx950)  — round 3
// B=32, CIN=128, L=4096, COUT=256, K=5, replication pad 2.
//   prep_kernel: x f32 -> XqT bf16 [B][4100][128] (quantized+transposed+pad),
//                W int32 -> Wt bf16 [5][256][128]
//   conv_kernel: LDS-staged X tile (XOR-swizzled), 64co x 64l wave tiles,
//                bf16 MFMA 16x16x32 (exact int arithmetic), int32 output.
// Round-2 post-mortem: conv was latency-bound (MfmaUtil 7%, VALU 7%, HBM 8%);
// fix = LDS staging + 4x4 acc tile + 2 blocks/CU.

#define B_    32
#define CIN   128
#define LEN   4096
#define COUT  256
#define KW    5
#define LROWS 4100  // LEN + 4 pad rows

#define XQT_USHORTS ((size_t)B_ * LROWS * CIN)  // 16,793,600
#define WT_USHORTS  ((size_t)KW * COUT * CIN)   // 163,840

typedef float          f32x4 __attribute__((ext_vector_type(4)));
typedef short          s16x8 __attribute__((ext_vector_type(8)));
typedef unsigned short u16;
typedef u16            u16x4 __attribute__((ext_vector_type(4)));

// round-half-even(x/0.05) - 3, clip to [-128,127], as bf16 bit pattern.
// IEEE division to match jnp bit-for-bit; integers |v|<=128 exact in bf16.
__device__ __forceinline__ u16 quant_bf16(float xv) {
    float q = rintf(__fdiv_rn(xv, 0.05f)) - 3.0f;
    q = fminf(fmaxf(q, -128.0f), 127.0f);
    return (u16)(__float_as_uint(q) >> 16);
}

__global__ __launch_bounds__(256) void prep_kernel(
        const float* __restrict__ x, const int* __restrict__ w,
        u16* __restrict__ xqt, u16* __restrict__ wt)
{
    int bid = blockIdx.x;
    int t   = threadIdx.x;
    if (bid < 512) {
        // ---- X: quantize + transpose one [128 ci][256 l] slab ----
        int b = bid >> 4, slab = bid & 15;
        int l0 = slab << 8;
        const float* xb = x + (size_t)b * CIN * LEN;
        u16* ob = xqt + (size_t)b * LROWS * CIN;
        #pragma unroll
        for (int i = 0; i < 8; ++i) {
            int st = t + (i << 8);            // 4ci x 4l subtiles; lanes consecutive in l
            int l4 = st & 63, c4 = st >> 6;
            int ci = c4 << 2, ll = (l4 << 2) + l0;
            u16 q[4][4];
            #pragma unroll
            for (int j = 0; j < 4; ++j) {
                f32x4 f = *(const f32x4*)(xb + (size_t)(ci + j) * LEN + ll);
                #pragma unroll
                for (int m = 0; m < 4; ++m) q[j][m] = quant_bf16(f[m]);
            }
            #pragma unroll
            for (int m = 0; m < 4; ++m) {     // 4x4 register transpose, 8B stores
                u16x4 v = { q[0][m], q[1][m], q[2][m], q[3][m] };
                *(u16x4*)(ob + (size_t)(2 + ll + m) * CIN + ci) = v;
            }
        }
        // ---- replication pad rows ----
        if (slab == 0 && t < 32) {
            int ci = t << 2;
            u16 q[4];
            #pragma unroll
            for (int j = 0; j < 4; ++j) q[j] = quant_bf16(xb[(size_t)(ci + j) * LEN]);
            u16x4 v = { q[0], q[1], q[2], q[3] };
            *(u16x4*)(ob + ci) = v;
            *(u16x4*)(ob + CIN + ci) = v;
        }
        if (slab == 15 && t >= 32 && t < 64) {
            int ci = (t - 32) << 2;
            u16 q[4];
            #pragma unroll
            for (int j = 0; j < 4; ++j) q[j] = quant_bf16(xb[(size_t)(ci + j) * LEN + (LEN - 1)]);
            u16x4 v = { q[0], q[1], q[2], q[3] };
            *(u16x4*)(ob + (size_t)4098 * CIN + ci) = v;
            *(u16x4*)(ob + (size_t)4099 * CIN + ci) = v;
        }
    } else {
        // ---- W: [256 co][128 ci][5 k] int32 -> Wt bf16 [5 k][256 co][128 ci] ----
        int o  = ((bid - 512) << 8) + t;
        int c4 = o & 31, co = (o >> 5) & 255, k = o >> 13;
        int ci = c4 << 2;
        u16 q[4];
        #pragma unroll
        for (int j = 0; j < 4; ++j) {
            float f = (float)w[co * (CIN * KW) + (ci + j) * KW + k];  // |v|<=127 exact
            q[j] = (u16)(__float_as_uint(f) >> 16);
        }
        u16x4 v4 = { q[0], q[1], q[2], q[3] };
        *(u16x4*)(wt + ((size_t)k * COUT + co) * CIN + ci) = v4;
    }
}

// Swizzled LDS read: row stride is 256B (bank-aliasing); XOR the 16B-chunk
// index with (row&7) so the 16 lanes of a ds_read_b128 spread across banks.
__device__ __forceinline__ s16x8 lds_read(const u16* smem, int row, int ci0) {
    int byte = (row << 8) + ((((ci0 >> 3) ^ (row & 7))) << 4);
    return *(const s16x8*)((const char*)smem + byte);
}

// Block: 256 co x 128 l.  8 waves = 4 co-waves x 2 l-waves; wave = 64co x 64l.
// X tile [132 rows][128 ci] staged in LDS (33.8 KB, XOR-swizzled).
// W read from global (320 KB total, L1/L2-resident, 4x intra-block reuse).
__global__ __launch_bounds__(512, 4) void conv_kernel(
        const u16* __restrict__ xqt, const u16* __restrict__ wt,
        const int* __restrict__ bias, const float* __restrict__ wscale,
        int* __restrict__ out)
{
    __shared__ u16 smem[132 * CIN];   // 33,792 B

    int bid = blockIdx.x;
    int b  = bid >> 5;
    int l0 = (bid & 31) << 7;
    int tid = threadIdx.x;
    int wid = tid >> 6, lane = tid & 63;
    int co_base = (wid & 3) << 6;         // 4 co-waves x 64
    int wl      = (wid >> 2) << 6;        // 2 l-waves x 64 (local l base)
    int lr = lane & 15, lh = lane >> 4;

    // ---- stage X tile: rows l0..l0+131 of XqT[b] (pads pre-materialized) ----
    const u16* xb = xqt + ((size_t)b * LROWS + l0) * CIN;
    #pragma unroll
    for (int it = 0; it < 4; ++it) {
        int id = it * 512 + tid;          // 16B chunk id, 0..2047
        int r = id >> 4, c = id & 15;
        s16x8 v = *(const s16x8*)(xb + r * CIN + c * 8);
        *(s16x8*)((char*)smem + (r << 8) + ((c ^ (r & 7)) << 4)) = v;
    }
    if (tid < 64) {                       // tail chunks 2048..2111
        int id = 2048 + tid;
        int r = id >> 4, c = id & 15;
        s16x8 v = *(const s16x8*)(xb + r * CIN + c * 8);
        *(s16x8*)((char*)smem + (r << 8) + ((c ^ (r & 7)) << 4)) = v;
    }
    __syncthreads();

    // ---- K-loop: 5 taps x 4 ci-quarters, 16 MFMAs per step ----
    f32x4 acc[4][4] = {};
    #pragma unroll
    for (int k = 0; k < KW; ++k) {
        #pragma unroll
        for (int s = 0; s < 4; ++s) {
            int ci0 = (s << 5) + (lh << 3);
            s16x8 af[4];
            #pragma unroll
            for (int ct = 0; ct < 4; ++ct)
                af[ct] = *(const s16x8*)(wt + ((size_t)k * COUT + co_base + ct * 16 + lr) * CIN + ci0);
            s16x8 bf[4];
            #pragma unroll
            for (int lt = 0; lt < 4; ++lt)
                bf[lt] = lds_read(smem, wl + lt * 16 + lr + k, ci0);
            #pragma unroll
            for (int ct = 0; ct < 4; ++ct) {
                #pragma unroll
                for (int lt = 0; lt < 4; ++lt)
                    acc[ct][lt] = __builtin_amdgcn_mfma_f32_16x16x32_bf16(
                        af[ct], bf[lt], acc[ct][lt], 0, 0, 0);
            }
        }
    }

    // ---- requant epilogue (exact reference arithmetic), int32 stores ----
    #pragma unroll
    for (int ct = 0; ct < 4; ++ct) {
        #pragma unroll
        for (int r = 0; r < 4; ++r) {
            int co = co_base + ct * 16 + (lh << 2) + r;
            float sc = __fdiv_rn(__fmul_rn(0.05f, wscale[co]), 0.1f);
            float bs = (float)bias[co];
            #pragma unroll
            for (int lt = 0; lt < 4; ++lt) {
                int l = l0 + wl + lt * 16 + lr;
                float a = __fadd_rn(acc[ct][lt][r], bs);
                float o = __fadd_rn(__fmul_rn(a, sc), -128.0f);
                o = rintf(o);
                o = fminf(fmaxf(o, -128.0f), 127.0f);
                out[((size_t)b * COUT + co) * LEN + l] = (int)o;
            }
        }
    }
}

extern "C" void kernel_launch(void* const* d_in, const int* in_sizes, int n_in,
                              void* d_out, int out_size, void* d_ws, size_t ws_size,
                              hipStream_t stream)
{
    const float* x    = (const float*)d_in[0];
    const int*   w    = (const int*)d_in[1];
    const int*   bias = (const int*)d_in[2];
    const float* wsc  = (const float*)d_in[3];
    int* out = (int*)d_out;

    u16* xqt = (u16*)d_ws;
    u16* wt  = xqt + XQT_USHORTS;   // needs 33,914,880 bytes total

    prep_kernel<<<dim3(512 + 160), dim3(256), 0, stream>>>(x, w, xqt, wt);
    conv_kernel<<<dim3(B_ * (LEN / 128)), dim3(512), 0, stream>>>(xqt, wt, bias, wsc, out);
}

// Round 4
// 92.792 us; speedup vs baseline: 2.8628x; 1.5268x over previous
//
#include <hip/hip_runtime.h>

// QuantizedConv1d on MI355X (gfx950) — round 4
// B=32, CIN=128, L=4096, COUT=256, K=5, replication pad 2.
//   wprep_kernel: W int32 -> Wt bf16 [5][256][128]  (tiny)
//   conv_fused:   x f32 read directly, quantize+transpose into swizzled LDS,
//                 bf16 MFMA 16x16x32 (exact int arithmetic), int32 output.
// Round-3 post-mortem: conv latency-bound (MfmaUtil 16%) — launch_bounds
// strangled regs (no pipelining) and W loads per step too frequent.
// Fix: fuse prep (removes 36us + 67MB round-trip), 32co x 128l wave tile
// (half the W-load rate), register W-frag prefetch per tap, no reg cap.

#define B_    32
#define CIN   128
#define LEN   4096
#define COUT  256
#define KW    5
#define LTROWS 264   // staged l rows: gl in [l0-4, l0+259], rows 2..261 used

typedef float          f32x4 __attribute__((ext_vector_type(4)));
typedef short          s16x8 __attribute__((ext_vector_type(8)));
typedef unsigned short u16;
typedef u16            u16x4 __attribute__((ext_vector_type(4)));

// round-half-even(x/0.05) - 3, clip to [-128,127], as bf16 bit pattern.
// IEEE division to match jnp bit-for-bit; integers |v|<=128 exact in bf16.
__device__ __forceinline__ u16 quant_bf16(float xv) {
    float q = rintf(__fdiv_rn(xv, 0.05f)) - 3.0f;
    q = fminf(fmaxf(q, -128.0f), 127.0f);
    return (u16)(__float_as_uint(q) >> 16);
}

__global__ __launch_bounds__(256) void wprep_kernel(
        const int* __restrict__ w, u16* __restrict__ wt)
{
    int o  = blockIdx.x * 256 + threadIdx.x;   // 40960 total, 4 ci each
    int c4 = o & 31, co = (o >> 5) & 255, k = o >> 13;
    int ci = c4 << 2;
    u16 q[4];
    #pragma unroll
    for (int j = 0; j < 4; ++j) {
        float f = (float)w[co * (CIN * KW) + (ci + j) * KW + k];  // |v|<=127 exact
        q[j] = (u16)(__float_as_uint(f) >> 16);
    }
    u16x4 v4 = { q[0], q[1], q[2], q[3] };
    *(u16x4*)(wt + ((size_t)k * COUT + co) * CIN + ci) = v4;
}

// Swizzled LDS addressing: row stride 256B aliases banks; XOR the 16B-chunk
// index with (row&7). Write side (8B granular) and read side (16B) agree.
__device__ __forceinline__ void stage_write(u16* smem, int row, int ci, u16x4 v) {
    int byte = (row << 8) + (((ci >> 3) ^ (row & 7)) << 4) + ((ci & 4) << 1);
    *(u16x4*)((char*)smem + byte) = v;
}

// Block: 128 co x 256 l. 8 waves = 4 co-waves x 2 l-waves; wave = 32co x 128l.
// LDS: X tile [264 rows][128 ci] bf16, XOR-swizzled (67,584 B).
// W read from global (L2-resident, 8 l-tiles reuse per fragment).
__global__ __launch_bounds__(512) void conv_fused(
        const float* __restrict__ x, const u16* __restrict__ wt,
        const int* __restrict__ bias, const float* __restrict__ wscale,
        int* __restrict__ out)
{
    __shared__ u16 smem[LTROWS * CIN];   // 67,584 B

    int bid    = blockIdx.x;
    int b      = bid >> 5;
    int sub    = bid & 31;
    int ltile  = sub >> 1, cotile = sub & 1;
    int l0     = ltile << 8;
    int tid    = threadIdx.x;
    int wid    = tid >> 6, lane = tid & 63;
    int lr     = lane & 15, lh = lane >> 4;
    int cog    = (cotile << 7) + ((wid & 3) << 5);   // wave co base (0..224)
    int wl     = (wid >> 2) << 7;                    // wave local-l base {0,128}

    const float* xb = x + (size_t)b * CIN * LEN;

    // ---- stage: quantize + transpose x[b][*][l0-4 .. l0+259] into LDS ----
    // LDS row r <-> global l = l0 - 4 + r (clamped at edges).
    bool interior = (ltile >= 1) && (ltile <= 14);
    if (interior) {
        const float* xs = xb + (l0 - 4);             // 16B-aligned rows
        #pragma unroll
        for (int it = 0; it < 4; ++it) {
            int p  = (it << 9) + tid;                // 4ci x 4l patches
            int lg = p & 63, cg = p >> 6;            // lanes consecutive in l
            int ci = cg << 2, r0 = lg << 2;
            u16 q[4][4];
            #pragma unroll
            for (int j = 0; j < 4; ++j) {
                f32x4 f = *(const f32x4*)(xs + (size_t)(ci + j) * LEN + r0);
                #pragma unroll
                for (int m = 0; m < 4; ++m) q[j][m] = quant_bf16(f[m]);
            }
            #pragma unroll
            for (int m = 0; m < 4; ++m) {
                u16x4 v = { q[0][m], q[1][m], q[2][m], q[3][m] };
                stage_write(smem, r0 + m, ci, v);
            }
        }
        if (tid < 64) {                              // tail rows 256..263
            int cg = tid & 31, ci = cg << 2;
            int r0 = 256 + ((tid >> 5) << 2);
            u16 q[4][4];
            #pragma unroll
            for (int j = 0; j < 4; ++j) {
                f32x4 f = *(const f32x4*)(xs + (size_t)(ci + j) * LEN + r0);
                #pragma unroll
                for (int m = 0; m < 4; ++m) q[j][m] = quant_bf16(f[m]);
            }
            #pragma unroll
            for (int m = 0; m < 4; ++m) {
                u16x4 v = { q[0][m], q[1][m], q[2][m], q[3][m] };
                stage_write(smem, r0 + m, ci, v);
            }
        }
    } else {
        // edge blocks: scalar loads with replication clamp
        #pragma unroll
        for (int it = 0; it < 4; ++it) {
            int p  = (it << 9) + tid;
            int lg = p & 63, cg = p >> 6;
            int ci = cg << 2, r0 = lg << 2;
            u16 q[4][4];
            #pragma unroll
            for (int j = 0; j < 4; ++j)
                #pragma unroll
                for (int m = 0; m < 4; ++m) {
                    int gl = l0 - 4 + r0 + m;
                    gl = min(max(gl, 0), LEN - 1);
                    q[j][m] = quant_bf16(xb[(size_t)(ci + j) * LEN + gl]);
                }
            #pragma unroll
            for (int m = 0; m < 4; ++m) {
                u16x4 v = { q[0][m], q[1][m], q[2][m], q[3][m] };
                stage_write(smem, r0 + m, ci, v);
            }
        }
        if (tid < 64) {
            int cg = tid & 31, ci = cg << 2;
            int r0 = 256 + ((tid >> 5) << 2);
            u16 q[4][4];
            #pragma unroll
            for (int j = 0; j < 4; ++j)
                #pragma unroll
                for (int m = 0; m < 4; ++m) {
                    int gl = l0 - 4 + r0 + m;
                    gl = min(max(gl, 0), LEN - 1);
                    q[j][m] = quant_bf16(xb[(size_t)(ci + j) * LEN + gl]);
                }
            #pragma unroll
            for (int m = 0; m < 4; ++m) {
                u16x4 v = { q[0][m], q[1][m], q[2][m], q[3][m] };
                stage_write(smem, r0 + m, ci, v);
            }
        }
    }
    __syncthreads();

    // ---- K-loop: 5 taps; per tap prefetch 8 W-frags, then 4 ci-quarters ----
    f32x4 acc[2][8] = {};
    #pragma unroll
    for (int k = 0; k < KW; ++k) {
        s16x8 af[4][2];
        #pragma unroll
        for (int s = 0; s < 4; ++s)
            #pragma unroll
            for (int ct = 0; ct < 2; ++ct)
                af[s][ct] = *(const s16x8*)(
                    wt + ((size_t)k * COUT + cog + ct * 16 + lr) * CIN + (s << 5) + (lh << 3));
        #pragma unroll
        for (int s = 0; s < 4; ++s) {
            int chunk = (s << 2) + lh;
            #pragma unroll
            for (int lt = 0; lt < 8; ++lt) {
                int row = wl + (lt << 4) + lr + k + 2;
                s16x8 bf = *(const s16x8*)((const char*)smem +
                             (row << 8) + (((chunk ^ (row & 7)) << 4)));
                acc[0][lt] = __builtin_amdgcn_mfma_f32_16x16x32_bf16(af[s][0], bf, acc[0][lt], 0, 0, 0);
                acc[1][lt] = __builtin_amdgcn_mfma_f32_16x16x32_bf16(af[s][1], bf, acc[1][lt], 0, 0, 0);
            }
        }
    }

    // ---- requant epilogue (exact reference arithmetic), int32 stores ----
    size_t outb = (size_t)b * COUT * LEN;
    #pragma unroll
    for (int ct = 0; ct < 2; ++ct) {
        #pragma unroll
        for (int r = 0; r < 4; ++r) {
            int co = cog + ct * 16 + (lh << 2) + r;
            float scv = __fdiv_rn(__fmul_rn(0.05f, wscale[co]), 0.1f);
            float bs  = (float)bias[co];
            #pragma unroll
            for (int lt = 0; lt < 8; ++lt) {
                int l = l0 + wl + (lt << 4) + lr;
                float a = __fadd_rn(acc[ct][lt][r], bs);
                float o = __fadd_rn(__fmul_rn(a, scv), -128.0f);
                o = rintf(o);
                o = fminf(fmaxf(o, -128.0f), 127.0f);
                out[outb + (size_t)co * LEN + l] = (int)o;
            }
        }
    }
}

extern "C" void kernel_launch(void* const* d_in, const int* in_sizes, int n_in,
                              void* d_out, int out_size, void* d_ws, size_t ws_size,
                              hipStream_t stream)
{
    const float* x    = (const float*)d_in[0];
    const int*   w    = (const int*)d_in[1];
    const int*   bias = (const int*)d_in[2];
    const float* wsc  = (const float*)d_in[3];
    int* out = (int*)d_out;

    u16* wt = (u16*)d_ws;   // 327,680 bytes

    wprep_kernel<<<dim3(160), dim3(256), 0, stream>>>(w, wt);
    conv_fused<<<dim3(B_ * 32), dim3(512), 0, stream>>>(x, wt, bias, wsc, out);
}